// Round 6
// baseline (152.307 us; speedup 1.0000x reference)
//
#include <hip/hip_runtime.h>
#include <hip/hip_bf16.h>
#include <math.h>

// Problem constants (from reference setup_inputs)
#define B_ROWS 256
#define D_IN   128
#define D_OUT  256
#define M_LEN  4096
#define BETA   50.0f

// out layout (f32): loss[256] | mem_out[4096*256] | md_out[4096*128]
#define OFF_MEM  (B_ROWS)
#define OFF_MD   (B_ROWS + M_LEN * D_OUT)

// ws layout (float index): enc[65536] | pmin[512*32] | flags (ints)
#define ENC_F   0
#define PMIN_F  65536
#define FLAG_F  (65536 + 16384)   // flg[0..7]=group counters, flg[8]=done

#define TB 32
#define TM 64

// ---------------------------------------------------------------------------
// Single fused kernel, 512 blocks x 256 threads, all co-resident
// (LDS 48KB -> 3 blocks/CU; __launch_bounds__(256,2) -> >=2 blocks/CU;
//  512 = 2 x 256 CUs, so the producer/consumer spin cannot deadlock).
//
// Phase A (even blocks): compute one enc row = tanh(norm(x)@W1+b1); row
//   (bid>>1)^128 spreads producers across all b-tile groups. Release a
//   per-32-row group flag (store -> fence -> sync -> atomic release).
// Phase B (all blocks): issue ALL enc-independent global loads (memory
//   tiles + fused output-copy), THEN spin on the group flag (latency
//   hidden), then the r5-validated wave-private distance pipeline:
//   4-way k-split across waves, private LDS, zero main-loop barriers,
//   XOR-swizzled k-major tiles (2-way banks everywhere), 4x8 microtile.
//   Result: 32 per-(btile,mtile) row-mins -> pmin[bid*32+r].
// Tail: last block (done-counter) reduces pmin -> loss, writes out, and
//   runs the ballot/prefix circular-buffer scatter inline.
// ---------------------------------------------------------------------------
__global__ __launch_bounds__(256, 2) void k_all(
    const float* __restrict__ x, const float* __restrict__ mean,
    const float* __restrict__ stdv, const float* __restrict__ W1,
    const float* __restrict__ b1, const float* __restrict__ mem,
    const float4* __restrict__ mem4, const float4* __restrict__ md4,
    float* __restrict__ ws, float* __restrict__ out) {
  __shared__ __align__(16) float sE[4][32][TB];  // [wave][kk][row^swz] 16KB
  __shared__ __align__(16) float sM[4][32][TM];  // [wave][kk][row^swz] 32KB
  __shared__ int wcount[4];
  __shared__ int slast;

  float* enc  = ws + ENC_F;
  float* pmin = ws + PMIN_F;
  int*   flg  = (int*)(ws + FLAG_F);

  const int bid = blockIdx.x;   // 0..511
  const int t   = threadIdx.x;

  // ---- Phase A: even blocks produce one enc row ----
  if ((bid & 1) == 0) {
    const int row = (bid >> 1) ^ 128;  // producers spread across groups
    float* sx = &sE[0][0][0];
    if (t < D_IN) {
      float s = stdv[t];
      sx[t] = (s == 0.0f) ? 0.0f : (x[row * D_IN + t] - mean[t]) / s;
    }
    __syncthreads();
    float a0 = 0.f, a1 = 0.f, a2 = 0.f, a3 = 0.f;
#pragma unroll 8
    for (int k = 0; k < D_IN; k += 4) {
      a0 = fmaf(sx[k + 0], W1[(k + 0) * D_OUT + t], a0);
      a1 = fmaf(sx[k + 1], W1[(k + 1) * D_OUT + t], a1);
      a2 = fmaf(sx[k + 2], W1[(k + 2) * D_OUT + t], a2);
      a3 = fmaf(sx[k + 3], W1[(k + 3) * D_OUT + t], a3);
    }
    enc[row * D_OUT + t] = tanhf((a0 + a1) + (a2 + a3) + b1[t]);
    __threadfence();
    __syncthreads();
    if (t == 0)
      __hip_atomic_fetch_add(&flg[row >> 5], 1, __ATOMIC_RELEASE,
                             __HIP_MEMORY_SCOPE_AGENT);
  }

  // ---- Phase B: distance tile ----
  const int w  = t >> 6, l = t & 63;
  const int ro = l >> 3, q = l & 7;
  const int mtile = bid & 63, btile = bid >> 6;
  const int m0 = mtile * TM, b0 = btile * TB;

  // enc-independent loads first (copy + both memory chunks)
  float4 cm0 = mem4[bid * 512 + t];
  float4 cm1 = mem4[bid * 512 + 256 + t];
  float4 cd0 = md4[bid * 256 + t];

  const float* memp = mem + (m0 + ro) * D_OUT + w * 64 + q * 4;
  float4 rE[4], rM[8], rE2[4], rM2[8];
#pragma unroll
  for (int i = 0; i < 8; ++i) rM[i]  = *(const float4*)(memp + i * 8 * D_OUT);
#pragma unroll
  for (int i = 0; i < 8; ++i) rM2[i] = *(const float4*)(memp + 32 + i * 8 * D_OUT);

  // wait for this b-tile's 32 enc rows (spin hidden under loads above)
  if (t == 0) {
    while (__hip_atomic_load(&flg[btile], __ATOMIC_ACQUIRE,
                             __HIP_MEMORY_SCOPE_AGENT) < 32)
      __builtin_amdgcn_s_sleep(1);
  }
  __syncthreads();

  const float* encp = enc + (b0 + ro) * D_OUT + w * 64 + q * 4;
#pragma unroll
  for (int i = 0; i < 4; ++i) rE[i]  = *(const float4*)(encp + i * 8 * D_OUT);
#pragma unroll
  for (int i = 0; i < 4; ++i) rE2[i] = *(const float4*)(encp + 32 + i * 8 * D_OUT);

  float acc[4][8] = {};

  auto store_lds = [&](const float4* e, const float4* m) {
#pragma unroll
    for (int i = 0; i < 4; ++i) {
      const int row = (i * 8 + ro) ^ (q * 4);
      sE[w][q * 4 + 0][row] = e[i].x;
      sE[w][q * 4 + 1][row] = e[i].y;
      sE[w][q * 4 + 2][row] = e[i].z;
      sE[w][q * 4 + 3][row] = e[i].w;
    }
#pragma unroll
    for (int i = 0; i < 8; ++i) {
      const int row = (i * 8 + ro) ^ (q * 4);
      sM[w][q * 4 + 0][row] = m[i].x;
      sM[w][q * 4 + 1][row] = m[i].y;
      sM[w][q * 4 + 2][row] = m[i].z;
      sM[w][q * 4 + 3][row] = m[i].w;
    }
  };

  auto compute = [&]() {
#pragma unroll
    for (int kk = 0; kk < 32; ++kk) {
      const int sw = (kk >> 2) * 4;
      float4 a   = *(const float4*)&sE[w][kk][(ro * 4) ^ sw];
      float4 bv1 = *(const float4*)&sM[w][kk][(q * 8) ^ sw];
      float4 bv2 = *(const float4*)&sM[w][kk][(q * 8 + 4) ^ sw];
      float av[4] = {a.x, a.y, a.z, a.w};
      float bw[8] = {bv1.x, bv1.y, bv1.z, bv1.w, bv2.x, bv2.y, bv2.z, bv2.w};
#pragma unroll
      for (int i = 0; i < 4; ++i)
#pragma unroll
        for (int j = 0; j < 8; ++j)
          acc[i][j] += fabsf(av[i] - bw[j]);
    }
  };

  store_lds(rE, rM);
  compute();               // chunk 0
  store_lds(rE2, rM2);     // same-wave WAR: in-order LDS per wave
  compute();               // chunk 1

  // combine across the 4 k-quarter waves (own-region dump, one barrier)
  float* sf = &sM[0][0][0];
#pragma unroll
  for (int i = 0; i < 4; ++i)
#pragma unroll
    for (int j = 0; j < 8; ++j) {
      const int p = i * 8 + j;
      sf[w * 2048 + l * 32 + (p ^ (l & 31))] = acc[i][j];
    }
  __syncthreads();

  {
    const int r = t >> 3, cg = t & 7;
    const int lv = (r >> 2) * 8 + cg;
    float dmin = 3.4e38f;
#pragma unroll
    for (int j = 0; j < 8; ++j) {
      const int p = (r & 3) * 8 + j;
      float s = sf[0 * 2048 + lv * 32 + (p ^ (lv & 31))];
      s += sf[1 * 2048 + lv * 32 + (p ^ (lv & 31))];
      s += sf[2 * 2048 + lv * 32 + (p ^ (lv & 31))];
      s += sf[3 * 2048 + lv * 32 + (p ^ (lv & 31))];
      dmin = fminf(dmin, s);
    }
    dmin = fminf(dmin, __shfl_xor(dmin, 1));
    dmin = fminf(dmin, __shfl_xor(dmin, 2));
    dmin = fminf(dmin, __shfl_xor(dmin, 4));
    if (cg == 0) pmin[bid * 32 + r] = dmin;
  }

  // complete fused output copy (must precede done++)
  float4* mo = (float4*)(out + OFF_MEM);
  float4* dd = (float4*)(out + OFF_MD);
  mo[bid * 512 + t] = cm0;
  mo[bid * 512 + 256 + t] = cm1;
  dd[bid * 256 + t] = cd0;

  __threadfence();
  __syncthreads();
  if (t == 0) {
    int old = __hip_atomic_fetch_add(&flg[8], 1, __ATOMIC_ACQ_REL,
                                     __HIP_MEMORY_SCOPE_AGENT);
    __threadfence();
    slast = (old == 511) ? 1 : 0;
  }
  __syncthreads();
  if (!slast) return;

  // ---- last block: pmin -> loss, then circular-buffer scatter ----
  {
    const int btl = t >> 5, r = t & 31;
    float mn = 3.4e38f;
#pragma unroll 8
    for (int mt = 0; mt < 64; ++mt)
      mn = fminf(mn, __hip_atomic_load(&pmin[(btl * 64 + mt) * 32 + r],
                                       __ATOMIC_RELAXED,
                                       __HIP_MEMORY_SCOPE_AGENT));
    out[t] = mn;  // loss output

    bool cond = isfinite(mn) && (mn <= BETA);
    unsigned long long bm = __ballot(cond);
    int lane = t & 63, wv = t >> 6;
    int pre = __popcll(bm & ((1ull << lane) - 1ull));
    if (lane == 0) wcount[wv] = (int)__popcll(bm);
    __syncthreads();
    int base = 0;
    for (int wj = 0; wj < wv; ++wj) base += wcount[wj];
    if (cond) {
      int pos = base + pre;  // (M_LEN + prefix) % M_LEN
      float* mrow = out + OFF_MEM + pos * D_OUT;
      const float* erow = enc + t * D_OUT;
      for (int d = 0; d < D_OUT; ++d) mrow[d] = erow[d];
      float* drow = out + OFF_MD + pos * D_IN;
      const float* xrow = x + t * D_IN;
      for (int d = 0; d < D_IN; ++d) drow[d] = xrow[d];
    }
  }
}

// ---------------------------------------------------------------------------
extern "C" void kernel_launch(void* const* d_in, const int* in_sizes, int n_in,
                              void* d_out, int out_size, void* d_ws, size_t ws_size,
                              hipStream_t stream) {
  const float* x      = (const float*)d_in[0];
  const float* mean   = (const float*)d_in[1];
  const float* stdv   = (const float*)d_in[2];
  const float* W1     = (const float*)d_in[3];
  const float* b1     = (const float*)d_in[4];
  const float* memory = (const float*)d_in[5];
  const float* memdat = (const float*)d_in[6];
  float* out = (float*)d_out;
  float* ws  = (float*)d_ws;

  // zero the 9 flag ints each launch (graph-capture-safe)
  hipMemsetAsync((char*)d_ws + FLAG_F * sizeof(float), 0, 64, stream);

  k_all<<<dim3(512), dim3(256), 0, stream>>>(
      x, mean, stdv, W1, b1, memory,
      (const float4*)memory, (const float4*)memdat, ws, out);
}

// Round 7
// 80.327 us; speedup vs baseline: 1.8961x; 1.8961x over previous
//
#include <hip/hip_runtime.h>
#include <hip/hip_bf16.h>
#include <math.h>

// Problem constants (from reference setup_inputs)
#define B_ROWS 256
#define D_IN   128
#define D_OUT  256
#define M_LEN  4096
#define BETA   50.0f

// out layout (f32): loss[256] | mem_out[4096*256] | md_out[4096*128]
#define OFF_MEM  (B_ROWS)
#define OFF_MD   (B_ROWS + M_LEN * D_OUT)

// ws layout (float idx): enc[65536] | done-flag int
#define ENC_F   0
#define FLAG_F  65536

// ---------------------------------------------------------------------------
// K1 (k_prep): enc = tanh(norm(x)@W1+b1), loss init to +inf, zero done-flag.
// 256 blocks x 256 threads (one block per batch row).
// ---------------------------------------------------------------------------
__global__ __launch_bounds__(256) void k_prep(
    const float* __restrict__ x, const float* __restrict__ mean,
    const float* __restrict__ stdv, const float* __restrict__ W1,
    const float* __restrict__ b1, float* __restrict__ ws,
    float* __restrict__ out) {
  __shared__ float sx[D_IN];
  float* enc = ws + ENC_F;
  const int b = blockIdx.x, j = threadIdx.x;
  if (j < D_IN) {
    float s = stdv[j];
    sx[j] = (s == 0.0f) ? 0.0f : (x[b * D_IN + j] - mean[j]) / s;
  }
  __syncthreads();
  float acc = b1[j];
#pragma unroll 8
  for (int k = 0; k < D_IN; ++k) acc = fmaf(sx[k], W1[k * D_OUT + j], acc);
  enc[b * D_OUT + j] = tanhf(acc);
  if (b == 0) ((unsigned int*)out)[j] = 0x7F800000u;  // +inf loss init
  if (b == 0 && j == 0) ((int*)(ws + FLAG_F))[0] = 0;  // done-counter
}

// ---------------------------------------------------------------------------
// K2 (k_dist): loss[b] = min_m sum_d |enc[b,d] - memory[m,d]|
// 512 blocks (64 m-tiles x 8 b-tiles) x 256 threads. Tile 32b x 64m.
// k-split 4: wave w owns k in [64w, 64w+64), staged as 2 chunks of 32 into
// its PRIVATE LDS region -> NO barriers in the main loop (waves drift
// freely; SIMD interleaving hides LDS/global latency).
// Per lane: 4x8 microtile; LDS k-major, XOR swizzle row^=4*(k>>2) -> b32
// staging stores and b128 reads both 2-way (free). Staging loads are
// 8-lane-contiguous (128B runs). kk-loop unroll capped at 8 (I-cache:
// full unroll was ~36KB > 32KB L1I, and drifting waves thrash fetch).
// Fused FULL memory->out / mem_data->out copy (loads early, stores late).
// Tail: done-counter; last block runs the ballot/prefix circular-buffer
// scatter inline (saves the separate k_scatter launch).
// ---------------------------------------------------------------------------
#define TB 32
#define TM 64

__global__ __launch_bounds__(256) void k_dist(
    const float* __restrict__ x, const float* __restrict__ mem,
    const float4* __restrict__ mem4, const float4* __restrict__ md4,
    float* __restrict__ ws, float* __restrict__ out) {
  __shared__ __align__(16) float sE[4][32][TB];  // [wave][kk][row^swz] 16KB
  __shared__ __align__(16) float sM[4][32][TM];  // [wave][kk][row^swz] 32KB
  __shared__ int wcount[4];
  __shared__ int slast;

  float* enc = ws + ENC_F;
  int*   don = (int*)(ws + FLAG_F);

  const int t  = threadIdx.x;
  const int w  = t >> 6;     // wave id -> k-quarter
  const int l  = t & 63;
  const int ro = l >> 3;     // 0..7 staging row-offset; compute tr
  const int q  = l & 7;      // 0..7 staging f4-k index; compute tc
  const int m0 = blockIdx.x * TM;
  const int b0 = blockIdx.y * TB;
  const int bid = blockIdx.y * 64 + blockIdx.x;  // gridDim.x == 64

  const float* encp = enc + (b0 + ro) * D_OUT + w * 64 + q * 4;
  const float* memp = mem + (m0 + ro) * D_OUT + w * 64 + q * 4;

  float4 rE[4], rM[8], rE2[4], rM2[8];
  float acc[4][8] = {};

  auto store_lds = [&](const float4* e, const float4* m) {
#pragma unroll
    for (int i = 0; i < 4; ++i) {
      const int row = (i * 8 + ro) ^ (q * 4);
      sE[w][q * 4 + 0][row] = e[i].x;
      sE[w][q * 4 + 1][row] = e[i].y;
      sE[w][q * 4 + 2][row] = e[i].z;
      sE[w][q * 4 + 3][row] = e[i].w;
    }
#pragma unroll
    for (int i = 0; i < 8; ++i) {
      const int row = (i * 8 + ro) ^ (q * 4);
      sM[w][q * 4 + 0][row] = m[i].x;
      sM[w][q * 4 + 1][row] = m[i].y;
      sM[w][q * 4 + 2][row] = m[i].z;
      sM[w][q * 4 + 3][row] = m[i].w;
    }
  };

  auto compute = [&]() {
#pragma unroll 8
    for (int kk = 0; kk < 32; ++kk) {
      const int sw = (kk >> 2) * 4;
      float4 a   = *(const float4*)&sE[w][kk][(ro * 4) ^ sw];
      float4 bv1 = *(const float4*)&sM[w][kk][(q * 8) ^ sw];
      float4 bv2 = *(const float4*)&sM[w][kk][(q * 8 + 4) ^ sw];
      float av[4] = {a.x, a.y, a.z, a.w};
      float bw[8] = {bv1.x, bv1.y, bv1.z, bv1.w, bv2.x, bv2.y, bv2.z, bv2.w};
#pragma unroll
      for (int i = 0; i < 4; ++i)
#pragma unroll
        for (int j = 0; j < 8; ++j)
          acc[i][j] += fabsf(av[i] - bw[j]);
    }
  };

  // chunk 0 loads (coalesced: 8 consecutive lanes = 128B run)
#pragma unroll
  for (int i = 0; i < 4; ++i) rE[i] = *(const float4*)(encp + i * 8 * D_OUT);
#pragma unroll
  for (int i = 0; i < 8; ++i) rM[i] = *(const float4*)(memp + i * 8 * D_OUT);
  store_lds(rE, rM);

  // prefetch chunk 1 (+32 k)
#pragma unroll
  for (int i = 0; i < 4; ++i) rE2[i] = *(const float4*)(encp + 32 + i * 8 * D_OUT);
#pragma unroll
  for (int i = 0; i < 8; ++i) rM2[i] = *(const float4*)(memp + 32 + i * 8 * D_OUT);

  // fused output-copy loads (complete by the tail stores)
  float4 cm0 = mem4[bid * 512 + t];
  float4 cm1 = mem4[bid * 512 + 256 + t];
  float4 cd0 = md4[bid * 256 + t];

  compute();               // chunk 0
  store_lds(rE2, rM2);     // same-wave WAR on LDS: in-order per wave
  compute();               // chunk 1

  // ---- combine across the 4 k-quarter waves ----
  float* sf = &sM[0][0][0];
#pragma unroll
  for (int i = 0; i < 4; ++i)
#pragma unroll
    for (int j = 0; j < 8; ++j) {
      const int p = i * 8 + j;
      sf[w * 2048 + l * 32 + (p ^ (l & 31))] = acc[i][j];
    }
  __syncthreads();

  {
    const int r = t >> 3, cg = t & 7;
    const int lv = (r >> 2) * 8 + cg;
    float dmin = 3.4e38f;
#pragma unroll
    for (int j = 0; j < 8; ++j) {
      const int p = (r & 3) * 8 + j;
      float s = sf[0 * 2048 + lv * 32 + (p ^ (lv & 31))];
      s += sf[1 * 2048 + lv * 32 + (p ^ (lv & 31))];
      s += sf[2 * 2048 + lv * 32 + (p ^ (lv & 31))];
      s += sf[3 * 2048 + lv * 32 + (p ^ (lv & 31))];
      dmin = fminf(dmin, s);
    }
    dmin = fminf(dmin, __shfl_xor(dmin, 1));
    dmin = fminf(dmin, __shfl_xor(dmin, 2));
    dmin = fminf(dmin, __shfl_xor(dmin, 4));
    if (cg == 0)  // distances >= 0, init +inf -> uint-bit atomicMin valid
      atomicMin((unsigned int*)out + (b0 + r), __float_as_uint(dmin));
  }

  // ---- complete fused copy ----
  float4* mo = (float4*)(out + OFF_MEM);
  float4* dd = (float4*)(out + OFF_MD);
  mo[bid * 512 + t] = cm0;
  mo[bid * 512 + 256 + t] = cm1;
  dd[bid * 256 + t] = cd0;

  // ---- done-counter; last block performs the scatter update ----
  __threadfence();
  __syncthreads();
  if (t == 0) {
    int old = __hip_atomic_fetch_add(don, 1, __ATOMIC_ACQ_REL,
                                     __HIP_MEMORY_SCOPE_AGENT);
    slast = (old == 511) ? 1 : 0;
  }
  __syncthreads();
  if (!slast) return;

  {
    unsigned int lu = __hip_atomic_load((unsigned int*)out + t,
                                        __ATOMIC_RELAXED,
                                        __HIP_MEMORY_SCOPE_AGENT);
    float mn = __uint_as_float(lu);
    bool cond = isfinite(mn) && (mn <= BETA);
    unsigned long long bm = __ballot(cond);
    int lane = t & 63, wv = t >> 6;
    int pre = __popcll(bm & ((1ull << lane) - 1ull));
    if (lane == 0) wcount[wv] = (int)__popcll(bm);
    __syncthreads();
    int base = 0;
    for (int wj = 0; wj < wv; ++wj) base += wcount[wj];
    if (cond) {
      int pos = base + pre;  // (M_LEN + prefix) % M_LEN
      float* mrow = out + OFF_MEM + pos * D_OUT;
      const float* erow = enc + t * D_OUT;
      for (int d = 0; d < D_OUT; ++d) mrow[d] = erow[d];
      float* drow = out + OFF_MD + pos * D_IN;
      const float* xrow = x + t * D_IN;
      for (int d = 0; d < D_IN; ++d) drow[d] = xrow[d];
    }
  }
}

// ---------------------------------------------------------------------------
extern "C" void kernel_launch(void* const* d_in, const int* in_sizes, int n_in,
                              void* d_out, int out_size, void* d_ws, size_t ws_size,
                              hipStream_t stream) {
  const float* x      = (const float*)d_in[0];
  const float* mean   = (const float*)d_in[1];
  const float* stdv   = (const float*)d_in[2];
  const float* W1     = (const float*)d_in[3];
  const float* b1     = (const float*)d_in[4];
  const float* memory = (const float*)d_in[5];
  const float* memdat = (const float*)d_in[6];
  float* out = (float*)d_out;
  float* ws  = (float*)d_ws;

  k_prep<<<dim3(B_ROWS), dim3(256), 0, stream>>>(x, mean, stdv, W1, b1, ws, out);

  k_dist<<<dim3(M_LEN / TM, B_ROWS / TB), dim3(256), 0, stream>>>(
      x, memory, (const float4*)memory, (const float4*)memdat, ws, out);
}